// Round 10
// baseline (440.251 us; speedup 1.0000x reference)
//
#include <hip/hip_runtime.h>
#include <stdint.h>

// ---------- types / helpers ----------
typedef __attribute__((ext_vector_type(4))) float f32x4;
typedef __attribute__((ext_vector_type(8))) __bf16 bf16x8;
typedef __attribute__((ext_vector_type(8))) unsigned short u16x8;
typedef __attribute__((ext_vector_type(4))) unsigned short u16x4;

__device__ __forceinline__ float b2f(unsigned short u) {
  unsigned int x = ((unsigned int)u) << 16;
  float f; __builtin_memcpy(&f, &x, 4); return f;
}
__device__ __forceinline__ unsigned short f2b(float f) {
  unsigned int x; __builtin_memcpy(&x, &f, 4);
  x += 0x7fffu + ((x >> 16) & 1u);           // round-to-nearest-even
  return (unsigned short)(x >> 16);
}
__device__ __forceinline__ float sigmoidf(float x) {
  return 1.f / (1.f + __expf(-x));
}

// ---------- f32 -> bf16 transpose: in[R][C] f32 -> out[C][R] bf16 ----------
__global__ __launch_bounds__(256) void transpose_f2b(
    const float* __restrict__ in, unsigned short* __restrict__ out,
    int R, int C) {
  __shared__ unsigned short tile[64][72];
  const int r0 = blockIdx.y * 64, c0 = blockIdx.x * 64;
  const int tid = threadIdx.x;
  const int r = tid >> 3;             // 0..31
  const int c8 = (tid & 7) * 8;       // 0..56
#pragma unroll
  for (int i = 0; i < 2; i++) {
    const float* src = in + (size_t)(r0 + r + 32*i) * C + c0 + c8;
    f32x4 a = *(const f32x4*)src;
    f32x4 b = *(const f32x4*)(src + 4);
    unsigned short tmp[8];
#pragma unroll
    for (int j = 0; j < 4; j++) { tmp[j] = f2b(a[j]); tmp[4+j] = f2b(b[j]); }
    *(u16x8*)(&tile[r + 32*i][c8]) = *(u16x8*)tmp;
  }
  __syncthreads();
#pragma unroll
  for (int i = 0; i < 2; i++) {
    const int ro = r + 32*i;          // output row within tile (= input col)
    unsigned short tmp[8];
#pragma unroll
    for (int j = 0; j < 8; j++) tmp[j] = tile[c8 + j][ro];
    *(u16x8*)(out + (size_t)(c0 + ro) * R + r0 + c8) = *(u16x8*)tmp;
  }
}

// ---------- gather X = [rel|ent], ER = [ent|relation] (f32 in, bf16 out) ----------
__global__ void gather_all(const float* __restrict__ ent,
                           const float* __restrict__ rel,
                           const float* __restrict__ relation,
                           const int* __restrict__ cur, const int* __restrict__ prl,
                           unsigned short* __restrict__ Xall,
                           unsigned short* __restrict__ ERall) {
  const int row = blockIdx.x;          // t*512 + b, 0..4095
  const int b = row & 511;
  const int tid = threadIdx.x;         // 128 threads, each 8 elems of each 1024-row
  const int ci = cur[row], ri = prl[row];
  const float* xsrc = (tid < 64) ? (rel + (size_t)ri * 512 + tid * 8)
                                 : (ent + (size_t)ci * 512 + (tid - 64) * 8);
  const float* esrc = (tid < 64) ? (ent + (size_t)ci * 512 + tid * 8)
                                 : (relation + (size_t)b * 512 + (tid - 64) * 8);
  f32x4 xa = *(const f32x4*)xsrc, xb = *(const f32x4*)(xsrc + 4);
  f32x4 ea = *(const f32x4*)esrc, eb = *(const f32x4*)(esrc + 4);
  unsigned short xt[8], et[8];
#pragma unroll
  for (int j = 0; j < 4; j++) {
    xt[j] = f2b(xa[j]); xt[4+j] = f2b(xb[j]);
    et[j] = f2b(ea[j]); et[4+j] = f2b(eb[j]);
  }
  *(u16x8*)(Xall + (size_t)row * 1024 + tid * 8) = *(u16x8*)xt;
  *(u16x8*)(ERall + (size_t)row * 1024 + tid * 8) = *(u16x8*)et;
}

// ---------- bf16 MFMA GEMM, tile MT x NT (NT=128), 4 waves in 2x2 grid ----------
// C = A[M][K] * BT[N][K]^T (+pre bf16)(+bias f32)(relu).  Reg-staged, padded LDS.
// PERM_B: B row n reads physical row (n&3)*1024 + (n>>2)  (gate-interleave of Wx/Wh cols)
// LSTM_EP: fused LSTM gate epilogue. acc+pre+gatebias -> 4-lane shfl butterfly
//   gathers (i,f,g,o) per unit -> c,h; writes H bf16 (Cout, ldc) + C f32 (Cst).
// BT K index: keff = k < ksplit ? k+koff0 : k+koff1   (64-aligned split)
template<int MT, int NT, bool HAS_PRE, bool HAS_BIAS, bool DO_RELU, bool OUT_F32,
         bool PERM_B, bool LSTM_EP>
__global__ __launch_bounds__(256) void gemm_bf16(
    const unsigned short* __restrict__ A, int lda,
    const unsigned short* __restrict__ BT, int ldb,
    int K, int ksplit, int koff0, int koff1,
    const unsigned short* __restrict__ pre, int ldpre,
    const float* __restrict__ bias,
    void* __restrict__ Cout, int ldc,
    float* __restrict__ Cst) {
  constexpr int MF = MT / 32;                       // M fragments per wave
  constexpr int NF = NT / 32;                       // N fragments per wave
  __shared__ unsigned short As[MT][72];
  __shared__ unsigned short Bs[NT][72];
  const int tid = threadIdx.x;
  const int lane = tid & 63;
  const int w = tid >> 6;
  const int wr = w >> 1, wc = w & 1;                // 2x2 wave grid
  const int m0 = blockIdx.y * MT, n0 = blockIdx.x * NT;
  f32x4 acc[MF][NF] = {};
  const int rs = tid >> 3;                          // staging row 0..31
  const int cs = (tid & 7) * 8;                     // staging col chunk

  for (int k0 = 0; k0 < K; k0 += 64) {
    const int keff = (k0 < ksplit) ? (k0 + koff0) : (k0 + koff1);
#pragma unroll
    for (int i = 0; i < MT / 32; i++)
      *(u16x8*)(&As[rs + 32*i][cs]) =
          *(const u16x8*)(A + (size_t)(m0 + rs + 32*i) * lda + k0 + cs);
#pragma unroll
    for (int i = 0; i < NT / 32; i++) {
      const int brow = n0 + rs + 32*i;
      const int prow = PERM_B ? (((brow & 3) << 10) + (brow >> 2)) : brow;
      *(u16x8*)(&Bs[rs + 32*i][cs]) =
          *(const u16x8*)(BT + (size_t)prow * ldb + keff + cs);
    }
    __syncthreads();
#pragma unroll
    for (int ks = 0; ks < 2; ks++) {
      const int kb = ks * 32 + (lane >> 4) * 8;
      bf16x8 af[MF], bfr[NF];
#pragma unroll
      for (int m = 0; m < MF; m++)
        af[m] = *reinterpret_cast<const bf16x8*>(&As[wr*(MT/2) + m*16 + (lane & 15)][kb]);
#pragma unroll
      for (int n = 0; n < NF; n++)
        bfr[n] = *reinterpret_cast<const bf16x8*>(&Bs[wc*(NT/2) + n*16 + (lane & 15)][kb]);
#pragma unroll
      for (int m = 0; m < MF; m++)
#pragma unroll
        for (int n = 0; n < NF; n++)
          acc[m][n] = __builtin_amdgcn_mfma_f32_16x16x32_bf16(af[m], bfr[n], acc[m][n], 0, 0, 0);
    }
    __syncthreads();
  }

  // C/D layout: col = lane&15 (n), row = (lane>>4)*4 + r (m)  [verified m89]
  const int cn = lane & 15, rb = (lane >> 4) * 4;
#pragma unroll
  for (int m = 0; m < MF; m++) {
#pragma unroll
    for (int n = 0; n < NF; n++) {
      const int gn = n0 + wc*(NT/2) + n*16 + cn;
      if (LSTM_EP) {
        const int g = gn & 3, u = gn >> 2;
        const float gb = bias[g * 1024 + u];
#pragma unroll
        for (int r = 0; r < 4; r++) {
          const int row = m0 + wr*(MT/2) + m*16 + rb + r;
          float v = acc[m][n][r] + b2f(pre[(size_t)row * ldpre + gn]) + gb;
          const float zi = __shfl_xor(v, g);        // gate 0 (i)
          const float zf = __shfl_xor(v, g ^ 1);    // gate 1 (f)
          const float zg = __shfl_xor(v, g ^ 2);    // gate 2 (g)
          const float zo = __shfl_xor(v, g ^ 3);    // gate 3 (o)
          const float cnew = sigmoidf(zf) * Cst[(size_t)row * 1024 + u]
                           + sigmoidf(zi) * tanhf(zg);
          const float h = sigmoidf(zo) * tanhf(cnew);
          if (g == 0) {
            Cst[(size_t)row * 1024 + u] = cnew;
            ((unsigned short*)Cout)[(size_t)row * ldc + u] = f2b(h);
          }
        }
      } else {
#pragma unroll
        for (int r = 0; r < 4; r++) {
          const int gm = m0 + wr*(MT/2) + m*16 + rb + r;
          float v = acc[m][n][r];
          if (HAS_PRE)  v += b2f(pre[(size_t)gm * ldpre + gn]);
          if (HAS_BIAS) v += bias[gn];
          if (DO_RELU)  v = v > 0.f ? v : 0.f;
          if (OUT_F32)  ((float*)Cout)[(size_t)gm * ldc + gn] = v;
          else ((unsigned short*)Cout)[(size_t)gm * ldc + gn] = f2b(v);
        }
      }
    }
  }
}

// ---------- t=0 LSTM gate: z = P1[0] (permuted layout), c0 = 0 ----------
__global__ void lstm_gate0(const unsigned short* __restrict__ P1_,
                           const float* __restrict__ bias,
                           float* __restrict__ C, unsigned short* __restrict__ H) {
  const int idx = blockIdx.x * 256 + threadIdx.x;   // 512*1024
  const int b = idx >> 10, u = idx & 1023;
  u16x4 z4 = *(const u16x4*)(P1_ + (size_t)b * 4096 + 4 * u);
  const float i_ = b2f(z4[0]) + bias[u];
  const float g_ = b2f(z4[2]) + bias[2048 + u];
  const float o_ = b2f(z4[3]) + bias[3072 + u];
  const float c = sigmoidf(i_) * tanhf(g_);         // f-gate * 0 drops out
  const float h = sigmoidf(o_) * tanhf(c);
  C[idx] = c;
  H[idx] = f2b(h);
}

// ---------- candidate scoring + softmax: one block per (t,b) row ----------
__global__ __launch_bounds__(256) void score_softmax(
    const unsigned short* __restrict__ F2,   // [4096][1024] bf16
    const float* __restrict__ rel,           // [5000][512] f32
    const float* __restrict__ ent,           // [50000][512] f32
    const int* __restrict__ crel, const int* __restrict__ cent, // [4096][32]
    float* __restrict__ outp) {              // [4096][32] f32
  const int b = blockIdx.x;                  // 0..4095
  const int tid = threadIdx.x;
  const int lane = tid & 63, w = tid >> 6;
  __shared__ float feat[1024];
  __shared__ float logits[32];
  {
    u16x4 fv = ((const u16x4*)(F2 + (size_t)b * 1024))[tid];
#pragma unroll
    for (int j = 0; j < 4; j++) feat[tid * 4 + j] = b2f(fv[j]);
  }
  __syncthreads();
  for (int k = w; k < 32; k += 4) {
    const int ri = crel[b * 32 + k], ei = cent[b * 32 + k];
    const float* rp = rel + (size_t)ri * 512 + lane * 8;
    const float* ep = ent + (size_t)ei * 512 + lane * 8;
    f32x4 r0 = *(const f32x4*)rp, r1 = *(const f32x4*)(rp + 4);
    f32x4 e0 = *(const f32x4*)ep, e1 = *(const f32x4*)(ep + 4);
    float sum = 0.f;
#pragma unroll
    for (int j = 0; j < 4; j++) {
      sum += r0[j] * feat[lane * 8 + j];
      sum += r1[j] * feat[lane * 8 + 4 + j];
      sum += e0[j] * feat[512 + lane * 8 + j];
      sum += e1[j] * feat[512 + lane * 8 + 4 + j];
    }
#pragma unroll
    for (int off = 32; off; off >>= 1) sum += __shfl_down(sum, off, 64);
    if (lane == 0) logits[k] = sum;
  }
  __syncthreads();
  if (tid < 32) {
    const float l = logits[tid];
    float mx = l;
#pragma unroll
    for (int off = 16; off; off >>= 1) mx = fmaxf(mx, __shfl_xor(mx, off, 32));
    const float p = __expf(l - mx);
    float s = p;
#pragma unroll
    for (int off = 16; off; off >>= 1) s += __shfl_xor(s, off, 32);
    outp[(size_t)b * 32 + tid] = p / s;
  }
}

// ---------- host launch ----------
extern "C" void kernel_launch(void* const* d_in, const int* in_sizes, int n_in,
                              void* d_out, int out_size, void* d_ws, size_t ws_size,
                              hipStream_t stream) {
  const float* ent      = (const float*)d_in[0];  // [50000][512]
  const float* rel      = (const float*)d_in[1];  // [5000][512]
  const float* relation = (const float*)d_in[2];  // [512][512]
  const float* Wx       = (const float*)d_in[3];  // [1024][4096]
  const float* Wh       = (const float*)d_in[4];  // [1024][4096]
  const float* bvec     = (const float*)d_in[5];  // [4096]
  const float* W1       = (const float*)d_in[6];  // [2048][1536]
  const float* b1       = (const float*)d_in[7];  // [1536]
  const float* W2       = (const float*)d_in[8];  // [1536][1024]
  const float* b2       = (const float*)d_in[9];  // [1024]
  const int* cur  = (const int*)d_in[10];  // [8][512]
  const int* prl  = (const int*)d_in[11];  // [8][512]
  const int* crel = (const int*)d_in[12];  // [8][512][32]
  const int* cent = (const int*)d_in[13];  // [8][512][32]
  float* out = (float*)d_out;              // [8][512][32] f32
  (void)in_sizes; (void)n_in; (void)out_size; (void)ws_size;

  char* wsp = (char*)d_ws;
  auto alloc = [&](size_t bytes) { char* p = wsp; wsp += (bytes + 255) & ~(size_t)255; return p; };
  unsigned short* WxT  = (unsigned short*)alloc((size_t)4096 * 1024 * 2);  // [4096][1024]
  unsigned short* WhT  = (unsigned short*)alloc((size_t)4096 * 1024 * 2);  // [4096][1024]
  unsigned short* W1T  = (unsigned short*)alloc((size_t)1536 * 2048 * 2);  // [1536][2048]
  unsigned short* W2T  = (unsigned short*)alloc((size_t)1024 * 1536 * 2);  // [1024][1536]
  unsigned short* Xall = (unsigned short*)alloc((size_t)4096 * 1024 * 2);  // [8*512][1024]
  unsigned short* ERall= (unsigned short*)alloc((size_t)4096 * 1024 * 2);  // [8*512][1024]
  unsigned short* P1   = (unsigned short*)alloc((size_t)4096 * 4096 * 2);  // [8*512][4096] perm cols
  unsigned short* P2   = (unsigned short*)alloc((size_t)4096 * 1536 * 2);  // [8*512][1536]
  unsigned short* Hall = (unsigned short*)alloc((size_t)4096 * 1024 * 2);  // [8*512][1024]
  unsigned short* F1   = (unsigned short*)alloc((size_t)4096 * 1536 * 2);  // [8*512][1536]
  unsigned short* F2   = (unsigned short*)alloc((size_t)4096 * 1024 * 2);  // [8*512][1024]
  float*          C    = (float*)         alloc((size_t)512 * 1024 * 4);   // [512][1024]

  const dim3 blk(256);
  const int BIG = 1 << 30;
  const size_t HS = (size_t)512 * 1024;    // per-step H elements

  // one-time (per launch) prep
  transpose_f2b<<<dim3(4096/64, 1024/64), blk, 0, stream>>>(Wx, WxT, 1024, 4096);
  transpose_f2b<<<dim3(4096/64, 1024/64), blk, 0, stream>>>(Wh, WhT, 1024, 4096);
  transpose_f2b<<<dim3(1536/64, 2048/64), blk, 0, stream>>>(W1, W1T, 2048, 1536);
  transpose_f2b<<<dim3(1024/64, 1536/64), blk, 0, stream>>>(W2, W2T, 1536, 1024);
  gather_all<<<4096, 128, 0, stream>>>(ent, rel, relation, cur, prl, Xall, ERall);

  // recurrence-independent big GEMMs
  // P1 = Xall @ Wx (gate-interleaved cols)   [4096,4096] k=1024
  gemm_bf16<128,128,false,false,false,false,true,false><<<dim3(32, 32), blk, 0, stream>>>(
      Xall, 1024, WxT, 1024, 1024, BIG, 0, 0, nullptr, 0, nullptr, P1, 4096, nullptr);
  // P2 = [ent|relation] @ W1(rows 0..511, 1536..2047)   [4096,1536] k=1024
  gemm_bf16<128,128,false,false,false,false,false,false><<<dim3(12, 32), blk, 0, stream>>>(
      ERall, 1024, W1T, 2048, 1024, 512, 0, 1024, nullptr, 0, nullptr, P2, 1536, nullptr);

  // sequential LSTM chain: t=0 gate-only (h0=0), then fused Z-GEMM+gate per step
  // (64x128 tiles, grid (32,8) -- round-7-proven geometry)
  lstm_gate0<<<2048, 256, 0, stream>>>(P1, bvec, C, Hall);
  for (int t = 1; t < 8; t++) {
    gemm_bf16<64,128,true,false,false,false,true,true><<<dim3(32, 8), blk, 0, stream>>>(
        Hall + (size_t)(t - 1) * HS, 1024, WhT, 1024, 1024, BIG, 0, 0,
        P1 + (size_t)t * 512 * 4096, 4096, bvec,
        Hall + (size_t)t * HS, 1024, C);
  }

  // batched posterior MLP over all 8 steps
  // F1 = relu(Hall @ W1(rows 512..1535) + P2 + b1)   [4096,1536] k=1024
  gemm_bf16<128,128,true,true,true,false,false,false><<<dim3(12, 32), blk, 0, stream>>>(
      Hall, 1024, W1T, 2048, 1024, BIG, 512, 0, P2, 1536, b1, F1, 1536, nullptr);
  // F2 = relu(F1 @ W2 + b2)                          [4096,1024] k=1536
  gemm_bf16<128,128,false,true,true,false,false,false><<<dim3(8, 32), blk, 0, stream>>>(
      F1, 1536, W2T, 1536, 1536, BIG, 0, 0, nullptr, 0, b2, F2, 1024, nullptr);
  // candidate scoring + softmax for all steps
  score_softmax<<<4096, 256, 0, stream>>>(F2, rel, ent, crel, cent, out);
}

// Round 11
// 358.358 us; speedup vs baseline: 1.2285x; 1.2285x over previous
//
#include <hip/hip_runtime.h>
#include <stdint.h>

// ---------- types / helpers ----------
typedef __attribute__((ext_vector_type(4))) float f32x4;
typedef __attribute__((ext_vector_type(8))) __bf16 bf16x8;
typedef __attribute__((ext_vector_type(8))) unsigned short u16x8;
typedef __attribute__((ext_vector_type(4))) unsigned short u16x4;

__device__ __forceinline__ float b2f(unsigned short u) {
  unsigned int x = ((unsigned int)u) << 16;
  float f; __builtin_memcpy(&f, &x, 4); return f;
}
__device__ __forceinline__ unsigned short f2b(float f) {
  unsigned int x; __builtin_memcpy(&x, &f, 4);
  x += 0x7fffu + ((x >> 16) & 1u);           // round-to-nearest-even
  return (unsigned short)(x >> 16);
}
__device__ __forceinline__ float sigmoidf(float x) {
  return 1.f / (1.f + __expf(-x));
}
__device__ __forceinline__ float tanh_fast(float x) {
  return 1.f - 2.f / (1.f + __expf(2.f * x));  // exact at +-inf, ~2ulp
}

// ---------- f32 -> bf16 transpose: in[R][C] f32 -> out[C][R] bf16 ----------
__global__ __launch_bounds__(256) void transpose_f2b(
    const float* __restrict__ in, unsigned short* __restrict__ out,
    int R, int C) {
  __shared__ unsigned short tile[64][72];
  const int r0 = blockIdx.y * 64, c0 = blockIdx.x * 64;
  const int tid = threadIdx.x;
  const int r = tid >> 3;             // 0..31
  const int c8 = (tid & 7) * 8;       // 0..56
#pragma unroll
  for (int i = 0; i < 2; i++) {
    const float* src = in + (size_t)(r0 + r + 32*i) * C + c0 + c8;
    f32x4 a = *(const f32x4*)src;
    f32x4 b = *(const f32x4*)(src + 4);
    unsigned short tmp[8];
#pragma unroll
    for (int j = 0; j < 4; j++) { tmp[j] = f2b(a[j]); tmp[4+j] = f2b(b[j]); }
    *(u16x8*)(&tile[r + 32*i][c8]) = *(u16x8*)tmp;
  }
  __syncthreads();
#pragma unroll
  for (int i = 0; i < 2; i++) {
    const int ro = r + 32*i;          // output row within tile (= input col)
    unsigned short tmp[8];
#pragma unroll
    for (int j = 0; j < 8; j++) tmp[j] = tile[c8 + j][ro];
    *(u16x8*)(out + (size_t)(c0 + ro) * R + r0 + c8) = *(u16x8*)tmp;
  }
}

// ---------- gather X = [rel|ent], ER = [ent|relation] (f32 in, bf16 out) ----------
__global__ void gather_all(const float* __restrict__ ent,
                           const float* __restrict__ rel,
                           const float* __restrict__ relation,
                           const int* __restrict__ cur, const int* __restrict__ prl,
                           unsigned short* __restrict__ Xall,
                           unsigned short* __restrict__ ERall) {
  const int row = blockIdx.x;          // t*512 + b, 0..4095
  const int b = row & 511;
  const int tid = threadIdx.x;         // 128 threads, each 8 elems of each 1024-row
  const int ci = cur[row], ri = prl[row];
  const float* xsrc = (tid < 64) ? (rel + (size_t)ri * 512 + tid * 8)
                                 : (ent + (size_t)ci * 512 + (tid - 64) * 8);
  const float* esrc = (tid < 64) ? (ent + (size_t)ci * 512 + tid * 8)
                                 : (relation + (size_t)b * 512 + (tid - 64) * 8);
  f32x4 xa = *(const f32x4*)xsrc, xb = *(const f32x4*)(xsrc + 4);
  f32x4 ea = *(const f32x4*)esrc, eb = *(const f32x4*)(esrc + 4);
  unsigned short xt[8], et[8];
#pragma unroll
  for (int j = 0; j < 4; j++) {
    xt[j] = f2b(xa[j]); xt[4+j] = f2b(xb[j]);
    et[j] = f2b(ea[j]); et[4+j] = f2b(eb[j]);
  }
  *(u16x8*)(Xall + (size_t)row * 1024 + tid * 8) = *(u16x8*)xt;
  *(u16x8*)(ERall + (size_t)row * 1024 + tid * 8) = *(u16x8*)et;
}

// ---------- bf16 MFMA GEMM, tile 128x128, 4 waves in 2x2 grid ----------
// C = A[M][K] * BT[N][K]^T (+pre bf16)(+bias f32)(relu).  Reg-staged, padded LDS.
// PERM_B: B row n reads physical row (n&3)*1024 + (n>>2)  (gate-interleave of Wx cols)
// BT K index: keff = k < ksplit ? k+koff0 : k+koff1   (64-aligned split)
template<bool HAS_PRE, bool HAS_BIAS, bool DO_RELU, bool PERM_B>
__global__ __launch_bounds__(256) void gemm_bf16(
    const unsigned short* __restrict__ A, int lda,
    const unsigned short* __restrict__ BT, int ldb,
    int K, int ksplit, int koff0, int koff1,
    const unsigned short* __restrict__ pre, int ldpre,
    const float* __restrict__ bias,
    unsigned short* __restrict__ Cout, int ldc) {
  __shared__ unsigned short As[128][72];
  __shared__ unsigned short Bs[128][72];
  const int tid = threadIdx.x;
  const int lane = tid & 63;
  const int w = tid >> 6;
  const int wr = w >> 1, wc = w & 1;                // 2x2 wave grid
  const int m0 = blockIdx.y * 128, n0 = blockIdx.x * 128;
  f32x4 acc[4][4] = {};
  const int rs = tid >> 3;                          // staging row 0..31
  const int cs = (tid & 7) * 8;                     // staging col chunk

  for (int k0 = 0; k0 < K; k0 += 64) {
    const int keff = (k0 < ksplit) ? (k0 + koff0) : (k0 + koff1);
#pragma unroll
    for (int i = 0; i < 4; i++)
      *(u16x8*)(&As[rs + 32*i][cs]) =
          *(const u16x8*)(A + (size_t)(m0 + rs + 32*i) * lda + k0 + cs);
#pragma unroll
    for (int i = 0; i < 4; i++) {
      const int brow = n0 + rs + 32*i;
      const int prow = PERM_B ? (((brow & 3) << 10) + (brow >> 2)) : brow;
      *(u16x8*)(&Bs[rs + 32*i][cs]) =
          *(const u16x8*)(BT + (size_t)prow * ldb + keff + cs);
    }
    __syncthreads();
#pragma unroll
    for (int ks = 0; ks < 2; ks++) {
      const int kb = ks * 32 + (lane >> 4) * 8;
      bf16x8 af[4], bfr[4];
#pragma unroll
      for (int m = 0; m < 4; m++)
        af[m] = *reinterpret_cast<const bf16x8*>(&As[wr*64 + m*16 + (lane & 15)][kb]);
#pragma unroll
      for (int n = 0; n < 4; n++)
        bfr[n] = *reinterpret_cast<const bf16x8*>(&Bs[wc*64 + n*16 + (lane & 15)][kb]);
#pragma unroll
      for (int m = 0; m < 4; m++)
#pragma unroll
        for (int n = 0; n < 4; n++)
          acc[m][n] = __builtin_amdgcn_mfma_f32_16x16x32_bf16(af[m], bfr[n], acc[m][n], 0, 0, 0);
    }
    __syncthreads();
  }

  // C/D layout: col = lane&15 (n), row = (lane>>4)*4 + r (m)  [verified m89]
  const int cn = lane & 15, rb = (lane >> 4) * 4;
#pragma unroll
  for (int m = 0; m < 4; m++) {
#pragma unroll
    for (int n = 0; n < 4; n++) {
      const int gn = n0 + wc*64 + n*16 + cn;
#pragma unroll
      for (int r = 0; r < 4; r++) {
        const int gm = m0 + wr*64 + m*16 + rb + r;
        float v = acc[m][n][r];
        if (HAS_PRE)  v += b2f(pre[(size_t)gm * ldpre + gn]);
        if (HAS_BIAS) v += bias[gn];
        if (DO_RELU)  v = v > 0.f ? v : 0.f;
        Cout[(size_t)gm * ldc + gn] = f2b(v);
      }
    }
  }
}

// ---------- fused Z-GEMM + LSTM gate, 8 waves, in-block split-K ----------
// Z = Hprev[512][1024] @ WhT^T (perm cols) + P1slice; gates -> c,h.
// Quads 0/1 each accumulate one K-half of the 64x128 tile; quad 1 ships acc
// via LDS; quad 0 combines and runs the deduplicated gate epilogue:
// 4x4 lane-register transpose (3 shfl_xor) so each lane computes ONE (c,h).
__global__ __launch_bounds__(512) void zgemm_lstm(
    const unsigned short* __restrict__ A,     // Hprev [512][1024]
    const unsigned short* __restrict__ BT,    // WhT [4096][1024]
    const unsigned short* __restrict__ pre,   // P1 slice [512][4096] (perm cols)
    const float* __restrict__ bias,           // [4096] gate-major i,f,g,o
    unsigned short* __restrict__ Hout,        // [512][1024]
    float* __restrict__ Cst) {                // [512][1024]
  __shared__ unsigned short As[2][64][72];
  __shared__ unsigned short Bs[2][128][72];
  __shared__ f32x4 accL[8][256];
  const int tid = threadIdx.x;
  const int lane = tid & 63;
  const int w = tid >> 6;            // 0..7
  const int q = w >> 2;              // K-half
  const int wq = w & 3;
  const int wr = wq >> 1, wc = wq & 1;
  const int m0 = blockIdx.y * 64, n0 = blockIdx.x * 128;
  f32x4 acc[2][4] = {};
  const int tq = tid & 255;          // thread id within quad
  const int rs = tq >> 3;            // 0..31
  const int cs = (tq & 7) * 8;

  for (int k0 = 0; k0 < 512; k0 += 64) {
    const int kk = q * 512 + k0;
#pragma unroll
    for (int i = 0; i < 2; i++)
      *(u16x8*)(&As[q][rs + 32*i][cs]) =
          *(const u16x8*)(A + (size_t)(m0 + rs + 32*i) * 1024 + kk + cs);
#pragma unroll
    for (int i = 0; i < 4; i++) {
      const int brow = n0 + rs + 32*i;
      const int prow = ((brow & 3) << 10) + (brow >> 2);
      *(u16x8*)(&Bs[q][rs + 32*i][cs]) =
          *(const u16x8*)(BT + (size_t)prow * 1024 + kk + cs);
    }
    __syncthreads();
#pragma unroll
    for (int ks = 0; ks < 2; ks++) {
      const int kb = ks * 32 + (lane >> 4) * 8;
      bf16x8 af[2], bfr[4];
#pragma unroll
      for (int m = 0; m < 2; m++)
        af[m] = *reinterpret_cast<const bf16x8*>(&As[q][wr*32 + m*16 + (lane & 15)][kb]);
#pragma unroll
      for (int n = 0; n < 4; n++)
        bfr[n] = *reinterpret_cast<const bf16x8*>(&Bs[q][wc*64 + n*16 + (lane & 15)][kb]);
#pragma unroll
      for (int m = 0; m < 2; m++)
#pragma unroll
        for (int n = 0; n < 4; n++)
          acc[m][n] = __builtin_amdgcn_mfma_f32_16x16x32_bf16(af[m], bfr[n], acc[m][n], 0, 0, 0);
    }
    __syncthreads();
  }

  if (q == 1) {
#pragma unroll
    for (int m = 0; m < 2; m++)
#pragma unroll
      for (int n = 0; n < 4; n++)
        accL[m*4 + n][tq] = acc[m][n];
  }
  __syncthreads();
  if (q == 0) {
    const int cn = lane & 15, rb = (lane >> 4) * 4, g = lane & 3;
#pragma unroll
    for (int m = 0; m < 2; m++) {
#pragma unroll
      for (int n = 0; n < 4; n++) {
        const f32x4 s4 = accL[m*4 + n][tq];
        const int gn = n0 + wc*64 + n*16 + cn;       // gn&3 == lane&3 == g
        const int u = gn >> 2;
        const float gb = bias[g * 1024 + u];
        const int row0 = m0 + wr*32 + m*16 + rb;
        const float v0 = acc[m][n][0] + s4[0] + b2f(pre[(size_t)(row0+0) * 4096 + gn]) + gb;
        const float v1 = acc[m][n][1] + s4[1] + b2f(pre[(size_t)(row0+1) * 4096 + gn]) + gb;
        const float v2 = acc[m][n][2] + s4[2] + b2f(pre[(size_t)(row0+2) * 4096 + gn]) + gb;
        const float v3 = acc[m][n][3] + s4[3] + b2f(pre[(size_t)(row0+3) * 4096 + gn]) + gb;
        // 4x4 transpose within the xor-group: lane g ends up with all 4 gates
        // of unit u at row row0+g.  For mask m: send v[g^m], receive gate g^m.
        auto sel = [&](int idx) {
          return idx == 0 ? v0 : idx == 1 ? v1 : idx == 2 ? v2 : v3;
        };
        const float own = sel(g);
        const float r1 = __shfl_xor(sel(g ^ 1), 1);
        const float r2 = __shfl_xor(sel(g ^ 2), 2);
        const float r3 = __shfl_xor(sel(g ^ 3), 3);
        const float zi = g==0 ? own : g==1 ? r1 : g==2 ? r2 : r3;
        const float zf = g==0 ? r1  : g==1 ? own: g==2 ? r3 : r2;
        const float zg_= g==0 ? r2  : g==1 ? r3 : g==2 ? own: r1;
        const float zo = g==0 ? r3  : g==1 ? r2 : g==2 ? r1 : own;
        const size_t hidx = (size_t)(row0 + g) * 1024 + u;
        const float cnew = sigmoidf(zf) * Cst[hidx] + sigmoidf(zi) * tanh_fast(zg_);
        const float h = sigmoidf(zo) * tanh_fast(cnew);
        Cst[hidx] = cnew;
        Hout[hidx] = f2b(h);
      }
    }
  }
}

// ---------- t=0 LSTM gate: z = P1[0] (permuted layout), c0 = 0 ----------
__global__ void lstm_gate0(const unsigned short* __restrict__ P1_,
                           const float* __restrict__ bias,
                           float* __restrict__ C, unsigned short* __restrict__ H) {
  const int idx = blockIdx.x * 256 + threadIdx.x;   // 512*1024
  const int b = idx >> 10, u = idx & 1023;
  u16x4 z4 = *(const u16x4*)(P1_ + (size_t)b * 4096 + 4 * u);
  const float i_ = b2f(z4[0]) + bias[u];
  const float g_ = b2f(z4[2]) + bias[2048 + u];
  const float o_ = b2f(z4[3]) + bias[3072 + u];
  const float c = sigmoidf(i_) * tanh_fast(g_);     // f-gate * 0 drops out
  const float h = sigmoidf(o_) * tanh_fast(c);
  C[idx] = c;
  H[idx] = f2b(h);
}

// ---------- candidate scoring + softmax: one block per (t,b) row ----------
__global__ __launch_bounds__(256) void score_softmax(
    const unsigned short* __restrict__ F2,   // [4096][1024] bf16
    const float* __restrict__ rel,           // [5000][512] f32
    const float* __restrict__ ent,           // [50000][512] f32
    const int* __restrict__ crel, const int* __restrict__ cent, // [4096][32]
    float* __restrict__ outp) {              // [4096][32] f32
  const int b = blockIdx.x;                  // 0..4095
  const int tid = threadIdx.x;
  const int lane = tid & 63, w = tid >> 6;
  __shared__ float feat[1024];
  __shared__ float logits[32];
  {
    u16x4 fv = ((const u16x4*)(F2 + (size_t)b * 1024))[tid];
#pragma unroll
    for (int j = 0; j < 4; j++) feat[tid * 4 + j] = b2f(fv[j]);
  }
  __syncthreads();
  for (int k = w; k < 32; k += 4) {
    const int ri = crel[b * 32 + k], ei = cent[b * 32 + k];
    const float* rp = rel + (size_t)ri * 512 + lane * 8;
    const float* ep = ent + (size_t)ei * 512 + lane * 8;
    f32x4 r0 = *(const f32x4*)rp, r1 = *(const f32x4*)(rp + 4);
    f32x4 e0 = *(const f32x4*)ep, e1 = *(const f32x4*)(ep + 4);
    float sum = 0.f;
#pragma unroll
    for (int j = 0; j < 4; j++) {
      sum += r0[j] * feat[lane * 8 + j];
      sum += r1[j] * feat[lane * 8 + 4 + j];
      sum += e0[j] * feat[512 + lane * 8 + j];
      sum += e1[j] * feat[512 + lane * 8 + 4 + j];
    }
#pragma unroll
    for (int off = 32; off; off >>= 1) sum += __shfl_down(sum, off, 64);
    if (lane == 0) logits[k] = sum;
  }
  __syncthreads();
  if (tid < 32) {
    const float l = logits[tid];
    float mx = l;
#pragma unroll
    for (int off = 16; off; off >>= 1) mx = fmaxf(mx, __shfl_xor(mx, off, 32));
    const float p = __expf(l - mx);
    float s = p;
#pragma unroll
    for (int off = 16; off; off >>= 1) s += __shfl_xor(s, off, 32);
    outp[(size_t)b * 32 + tid] = p / s;
  }
}

// ---------- host launch ----------
extern "C" void kernel_launch(void* const* d_in, const int* in_sizes, int n_in,
                              void* d_out, int out_size, void* d_ws, size_t ws_size,
                              hipStream_t stream) {
  const float* ent      = (const float*)d_in[0];  // [50000][512]
  const float* rel      = (const float*)d_in[1];  // [5000][512]
  const float* relation = (const float*)d_in[2];  // [512][512]
  const float* Wx       = (const float*)d_in[3];  // [1024][4096]
  const float* Wh       = (const float*)d_in[4];  // [1024][4096]
  const float* bvec     = (const float*)d_in[5];  // [4096]
  const float* W1       = (const float*)d_in[6];  // [2048][1536]
  const float* b1       = (const float*)d_in[7];  // [1536]
  const float* W2       = (const float*)d_in[8];  // [1536][1024]
  const float* b2       = (const float*)d_in[9];  // [1024]
  const int* cur  = (const int*)d_in[10];  // [8][512]
  const int* prl  = (const int*)d_in[11];  // [8][512]
  const int* crel = (const int*)d_in[12];  // [8][512][32]
  const int* cent = (const int*)d_in[13];  // [8][512][32]
  float* out = (float*)d_out;              // [8][512][32] f32
  (void)in_sizes; (void)n_in; (void)out_size; (void)ws_size;

  char* wsp = (char*)d_ws;
  auto alloc = [&](size_t bytes) { char* p = wsp; wsp += (bytes + 255) & ~(size_t)255; return p; };
  unsigned short* WxT  = (unsigned short*)alloc((size_t)4096 * 1024 * 2);  // [4096][1024]
  unsigned short* WhT  = (unsigned short*)alloc((size_t)4096 * 1024 * 2);  // [4096][1024]
  unsigned short* W1T  = (unsigned short*)alloc((size_t)1536 * 2048 * 2);  // [1536][2048]
  unsigned short* W2T  = (unsigned short*)alloc((size_t)1024 * 1536 * 2);  // [1024][1536]
  unsigned short* Xall = (unsigned short*)alloc((size_t)4096 * 1024 * 2);  // [8*512][1024]
  unsigned short* ERall= (unsigned short*)alloc((size_t)4096 * 1024 * 2);  // [8*512][1024]
  unsigned short* P1   = (unsigned short*)alloc((size_t)4096 * 4096 * 2);  // [8*512][4096] perm cols
  unsigned short* P2   = (unsigned short*)alloc((size_t)4096 * 1536 * 2);  // [8*512][1536]
  unsigned short* Hall = (unsigned short*)alloc((size_t)4096 * 1024 * 2);  // [8*512][1024]
  unsigned short* F1   = (unsigned short*)alloc((size_t)4096 * 1536 * 2);  // [8*512][1536]
  unsigned short* F2   = (unsigned short*)alloc((size_t)4096 * 1024 * 2);  // [8*512][1024]
  float*          C    = (float*)         alloc((size_t)512 * 1024 * 4);   // [512][1024]

  const dim3 blk(256);
  const int BIG = 1 << 30;
  const size_t HS = (size_t)512 * 1024;    // per-step H elements

  // one-time (per launch) prep
  transpose_f2b<<<dim3(4096/64, 1024/64), blk, 0, stream>>>(Wx, WxT, 1024, 4096);
  transpose_f2b<<<dim3(4096/64, 1024/64), blk, 0, stream>>>(Wh, WhT, 1024, 4096);
  transpose_f2b<<<dim3(1536/64, 2048/64), blk, 0, stream>>>(W1, W1T, 2048, 1536);
  transpose_f2b<<<dim3(1024/64, 1536/64), blk, 0, stream>>>(W2, W2T, 1536, 1024);
  gather_all<<<4096, 128, 0, stream>>>(ent, rel, relation, cur, prl, Xall, ERall);

  // recurrence-independent big GEMMs
  // P1 = Xall @ Wx (gate-interleaved cols)   [4096,4096] k=1024
  gemm_bf16<false,false,false,true><<<dim3(32, 32), blk, 0, stream>>>(
      Xall, 1024, WxT, 1024, 1024, BIG, 0, 0, nullptr, 0, nullptr, P1, 4096);
  // P2 = [ent|relation] @ W1(rows 0..511, 1536..2047)   [4096,1536] k=1024
  gemm_bf16<false,false,false,false><<<dim3(12, 32), blk, 0, stream>>>(
      ERall, 1024, W1T, 2048, 1024, 512, 0, 1024, nullptr, 0, nullptr, P2, 1536);

  // sequential LSTM chain: t=0 gate-only (h0=0), then fused Z-GEMM+gate per step
  lstm_gate0<<<2048, 256, 0, stream>>>(P1, bvec, C, Hall);
  for (int t = 1; t < 8; t++) {
    zgemm_lstm<<<dim3(32, 8), dim3(512), 0, stream>>>(
        Hall + (size_t)(t - 1) * HS, WhT,
        P1 + (size_t)t * 512 * 4096, bvec,
        Hall + (size_t)t * HS, C);
  }

  // batched posterior MLP over all 8 steps
  // F1 = relu(Hall @ W1(rows 512..1535) + P2 + b1)   [4096,1536] k=1024
  gemm_bf16<true,true,true,false><<<dim3(12, 32), blk, 0, stream>>>(
      Hall, 1024, W1T, 2048, 1024, BIG, 512, 0, P2, 1536, b1, F1, 1536);
  // F2 = relu(F1 @ W2 + b2)                          [4096,1024] k=1536
  gemm_bf16<false,true,true,false><<<dim3(8, 32), blk, 0, stream>>>(
      F1, 1536, W2T, 1536, 1536, BIG, 0, 0, nullptr, 0, b2, F2, 1024);
  // candidate scoring + softmax for all steps
  score_softmax<<<4096, 256, 0, stream>>>(F2, rel, ent, crel, cent, out);
}

// Round 12
// 348.183 us; speedup vs baseline: 1.2644x; 1.0292x over previous
//
#include <hip/hip_runtime.h>
#include <stdint.h>

// ---------- types / helpers ----------
typedef __attribute__((ext_vector_type(4))) float f32x4;
typedef __attribute__((ext_vector_type(8))) __bf16 bf16x8;
typedef __attribute__((ext_vector_type(8))) unsigned short u16x8;
typedef __attribute__((ext_vector_type(4))) unsigned short u16x4;

__device__ __forceinline__ float b2f(unsigned short u) {
  unsigned int x = ((unsigned int)u) << 16;
  float f; __builtin_memcpy(&f, &x, 4); return f;
}
__device__ __forceinline__ unsigned short f2b(float f) {
  unsigned int x; __builtin_memcpy(&x, &f, 4);
  x += 0x7fffu + ((x >> 16) & 1u);           // round-to-nearest-even
  return (unsigned short)(x >> 16);
}
__device__ __forceinline__ float sigmoidf(float x) {
  return 1.f / (1.f + __expf(-x));
}
__device__ __forceinline__ float tanh_fast(float x) {
  return 1.f - 2.f / (1.f + __expf(2.f * x));  // exact at +-inf, ~2ulp
}

// ---------- bulk f32 -> bf16 convert (8 elems/thread) ----------
__global__ __launch_bounds__(256) void conv_f2b(
    const float* __restrict__ in, unsigned short* __restrict__ out) {
  const int i = blockIdx.x * 256 + threadIdx.x;
  f32x4 a = *(const f32x4*)(in + (size_t)i * 8);
  f32x4 b = *(const f32x4*)(in + (size_t)i * 8 + 4);
  unsigned short t[8];
#pragma unroll
  for (int j = 0; j < 4; j++) { t[j] = f2b(a[j]); t[4+j] = f2b(b[j]); }
  *(u16x8*)(out + (size_t)i * 8) = *(u16x8*)t;
}

// ---------- f32 -> bf16 transpose: in[R][C] f32 -> out[C][R] bf16 ----------
__global__ __launch_bounds__(256) void transpose_f2b(
    const float* __restrict__ in, unsigned short* __restrict__ out,
    int R, int C) {
  __shared__ unsigned short tile[64][72];
  const int r0 = blockIdx.y * 64, c0 = blockIdx.x * 64;
  const int tid = threadIdx.x;
  const int r = tid >> 3;             // 0..31
  const int c8 = (tid & 7) * 8;       // 0..56
#pragma unroll
  for (int i = 0; i < 2; i++) {
    const float* src = in + (size_t)(r0 + r + 32*i) * C + c0 + c8;
    f32x4 a = *(const f32x4*)src;
    f32x4 b = *(const f32x4*)(src + 4);
    unsigned short tmp[8];
#pragma unroll
    for (int j = 0; j < 4; j++) { tmp[j] = f2b(a[j]); tmp[4+j] = f2b(b[j]); }
    *(u16x8*)(&tile[r + 32*i][c8]) = *(u16x8*)tmp;
  }
  __syncthreads();
#pragma unroll
  for (int i = 0; i < 2; i++) {
    const int ro = r + 32*i;          // output row within tile (= input col)
    unsigned short tmp[8];
#pragma unroll
    for (int j = 0; j < 8; j++) tmp[j] = tile[c8 + j][ro];
    *(u16x8*)(out + (size_t)(c0 + ro) * R + r0 + c8) = *(u16x8*)tmp;
  }
}

// ---------- gather X = [rel|ent], ER = [ent|relation] (bf16 tables) ----------
__global__ void gather_all(const unsigned short* __restrict__ entB,
                           const unsigned short* __restrict__ relB,
                           const unsigned short* __restrict__ relationB,
                           const int* __restrict__ cur, const int* __restrict__ prl,
                           unsigned short* __restrict__ Xall,
                           unsigned short* __restrict__ ERall) {
  const int row = blockIdx.x;          // t*512 + b, 0..4095
  const int b = row & 511;
  const int tid = threadIdx.x;         // 128 threads, each 8 bf16 of each 1024-row
  const int ci = cur[row], ri = prl[row];
  const unsigned short* xsrc = (tid < 64) ? (relB + (size_t)ri * 512 + tid * 8)
                                          : (entB + (size_t)ci * 512 + (tid - 64) * 8);
  const unsigned short* esrc = (tid < 64) ? (entB + (size_t)ci * 512 + tid * 8)
                                          : (relationB + (size_t)b * 512 + (tid - 64) * 8);
  *(u16x8*)(Xall + (size_t)row * 1024 + tid * 8) = *(const u16x8*)xsrc;
  *(u16x8*)(ERall + (size_t)row * 1024 + tid * 8) = *(const u16x8*)esrc;
}

// ---------- bf16 MFMA GEMM, tile 128x128, 4 waves in 2x2 grid ----------
// C = A[M][K] * BT[N][K]^T (+bias f32)(relu).  Reg-staged, padded LDS.
// PERM_B: B row n reads physical row (n&3)*1024 + (n>>2)  (gate-interleave of Wx cols)
// ASPLIT: A col k sources: k<512 -> A[row][k] (ent); k<1536 -> A2[row][k-512] (h);
//         else A[row][k-1024] (relation).  lda applies to both A and A2.
template<bool HAS_BIAS, bool DO_RELU, bool PERM_B, bool ASPLIT>
__global__ __launch_bounds__(256) void gemm_bf16(
    const unsigned short* __restrict__ A,
    const unsigned short* __restrict__ A2, int lda,
    const unsigned short* __restrict__ BT, int ldb, int K,
    const float* __restrict__ bias,
    unsigned short* __restrict__ Cout, int ldc) {
  __shared__ unsigned short As[128][72];
  __shared__ unsigned short Bs[128][72];
  const int tid = threadIdx.x;
  const int lane = tid & 63;
  const int w = tid >> 6;
  const int wr = w >> 1, wc = w & 1;                // 2x2 wave grid
  const int m0 = blockIdx.y * 128, n0 = blockIdx.x * 128;
  f32x4 acc[4][4] = {};
  const int rs = tid >> 3;                          // staging row 0..31
  const int cs = (tid & 7) * 8;                     // staging col chunk

  for (int k0 = 0; k0 < K; k0 += 64) {
    const unsigned short* asrc; int ac;
    if (ASPLIT) {
      if (k0 < 512)       { asrc = A;  ac = k0; }
      else if (k0 < 1536) { asrc = A2; ac = k0 - 512; }
      else                { asrc = A;  ac = k0 - 1024; }
    } else { asrc = A; ac = k0; }
#pragma unroll
    for (int i = 0; i < 4; i++)
      *(u16x8*)(&As[rs + 32*i][cs]) =
          *(const u16x8*)(asrc + (size_t)(m0 + rs + 32*i) * lda + ac + cs);
#pragma unroll
    for (int i = 0; i < 4; i++) {
      const int brow = n0 + rs + 32*i;
      const int prow = PERM_B ? (((brow & 3) << 10) + (brow >> 2)) : brow;
      *(u16x8*)(&Bs[rs + 32*i][cs]) =
          *(const u16x8*)(BT + (size_t)prow * ldb + k0 + cs);
    }
    __syncthreads();
#pragma unroll
    for (int ks = 0; ks < 2; ks++) {
      const int kb = ks * 32 + (lane >> 4) * 8;
      bf16x8 af[4], bfr[4];
#pragma unroll
      for (int m = 0; m < 4; m++)
        af[m] = *reinterpret_cast<const bf16x8*>(&As[wr*64 + m*16 + (lane & 15)][kb]);
#pragma unroll
      for (int n = 0; n < 4; n++)
        bfr[n] = *reinterpret_cast<const bf16x8*>(&Bs[wc*64 + n*16 + (lane & 15)][kb]);
#pragma unroll
      for (int m = 0; m < 4; m++)
#pragma unroll
        for (int n = 0; n < 4; n++)
          acc[m][n] = __builtin_amdgcn_mfma_f32_16x16x32_bf16(af[m], bfr[n], acc[m][n], 0, 0, 0);
    }
    __syncthreads();
  }

  // C/D layout: col = lane&15 (n), row = (lane>>4)*4 + r (m)  [verified m89]
  const int cn = lane & 15, rb = (lane >> 4) * 4;
#pragma unroll
  for (int m = 0; m < 4; m++) {
#pragma unroll
    for (int n = 0; n < 4; n++) {
      const int gn = n0 + wc*64 + n*16 + cn;
#pragma unroll
      for (int r = 0; r < 4; r++) {
        const int gm = m0 + wr*64 + m*16 + rb + r;
        float v = acc[m][n][r];
        if (HAS_BIAS) v += bias[gn];
        if (DO_RELU)  v = v > 0.f ? v : 0.f;
        Cout[(size_t)gm * ldc + gn] = f2b(v);
      }
    }
  }
}

// ---------- fused Z-GEMM + LSTM gate, 8 waves, in-block split-K ----------
__global__ __launch_bounds__(512) void zgemm_lstm(
    const unsigned short* __restrict__ A,     // Hprev [512][1024]
    const unsigned short* __restrict__ BT,    // WhT [4096][1024]
    const unsigned short* __restrict__ pre,   // P1 slice [512][4096] (perm cols)
    const float* __restrict__ bias,           // [4096] gate-major i,f,g,o
    unsigned short* __restrict__ Hout,        // [512][1024]
    float* __restrict__ Cst) {                // [512][1024]
  __shared__ unsigned short As[2][64][72];
  __shared__ unsigned short Bs[2][128][72];
  __shared__ f32x4 accL[8][256];
  const int tid = threadIdx.x;
  const int lane = tid & 63;
  const int w = tid >> 6;            // 0..7
  const int q = w >> 2;              // K-half
  const int wq = w & 3;
  const int wr = wq >> 1, wc = wq & 1;
  const int m0 = blockIdx.y * 64, n0 = blockIdx.x * 128;
  f32x4 acc[2][4] = {};
  const int tq = tid & 255;          // thread id within quad
  const int rs = tq >> 3;            // 0..31
  const int cs = (tq & 7) * 8;

  for (int k0 = 0; k0 < 512; k0 += 64) {
    const int kk = q * 512 + k0;
#pragma unroll
    for (int i = 0; i < 2; i++)
      *(u16x8*)(&As[q][rs + 32*i][cs]) =
          *(const u16x8*)(A + (size_t)(m0 + rs + 32*i) * 1024 + kk + cs);
#pragma unroll
    for (int i = 0; i < 4; i++) {
      const int brow = n0 + rs + 32*i;
      const int prow = ((brow & 3) << 10) + (brow >> 2);
      *(u16x8*)(&Bs[q][rs + 32*i][cs]) =
          *(const u16x8*)(BT + (size_t)prow * 1024 + kk + cs);
    }
    __syncthreads();
#pragma unroll
    for (int ks = 0; ks < 2; ks++) {
      const int kb = ks * 32 + (lane >> 4) * 8;
      bf16x8 af[2], bfr[4];
#pragma unroll
      for (int m = 0; m < 2; m++)
        af[m] = *reinterpret_cast<const bf16x8*>(&As[q][wr*32 + m*16 + (lane & 15)][kb]);
#pragma unroll
      for (int n = 0; n < 4; n++)
        bfr[n] = *reinterpret_cast<const bf16x8*>(&Bs[q][wc*64 + n*16 + (lane & 15)][kb]);
#pragma unroll
      for (int m = 0; m < 2; m++)
#pragma unroll
        for (int n = 0; n < 4; n++)
          acc[m][n] = __builtin_amdgcn_mfma_f32_16x16x32_bf16(af[m], bfr[n], acc[m][n], 0, 0, 0);
    }
    __syncthreads();
  }

  if (q == 1) {
#pragma unroll
    for (int m = 0; m < 2; m++)
#pragma unroll
      for (int n = 0; n < 4; n++)
        accL[m*4 + n][tq] = acc[m][n];
  }
  __syncthreads();
  if (q == 0) {
    const int cn = lane & 15, rb = (lane >> 4) * 4, g = lane & 3;
#pragma unroll
    for (int m = 0; m < 2; m++) {
#pragma unroll
      for (int n = 0; n < 4; n++) {
        const f32x4 s4 = accL[m*4 + n][tq];
        const int gn = n0 + wc*64 + n*16 + cn;       // gn&3 == lane&3 == g
        const int u = gn >> 2;
        const float gb = bias[g * 1024 + u];
        const int row0 = m0 + wr*32 + m*16 + rb;
        const float v0 = acc[m][n][0] + s4[0] + b2f(pre[(size_t)(row0+0) * 4096 + gn]) + gb;
        const float v1 = acc[m][n][1] + s4[1] + b2f(pre[(size_t)(row0+1) * 4096 + gn]) + gb;
        const float v2 = acc[m][n][2] + s4[2] + b2f(pre[(size_t)(row0+2) * 4096 + gn]) + gb;
        const float v3 = acc[m][n][3] + s4[3] + b2f(pre[(size_t)(row0+3) * 4096 + gn]) + gb;
        // 4x4 transpose within the xor-group: lane g -> all 4 gates of unit u, row row0+g
        auto sel = [&](int idx) {
          return idx == 0 ? v0 : idx == 1 ? v1 : idx == 2 ? v2 : v3;
        };
        const float own = sel(g);
        const float r1 = __shfl_xor(sel(g ^ 1), 1);
        const float r2 = __shfl_xor(sel(g ^ 2), 2);
        const float r3 = __shfl_xor(sel(g ^ 3), 3);
        const float zi = g==0 ? own : g==1 ? r1 : g==2 ? r2 : r3;
        const float zf = g==0 ? r1  : g==1 ? own: g==2 ? r3 : r2;
        const float zg_= g==0 ? r2  : g==1 ? r3 : g==2 ? own: r1;
        const float zo = g==0 ? r3  : g==1 ? r2 : g==2 ? r1 : own;
        const size_t hidx = (size_t)(row0 + g) * 1024 + u;
        const float cnew = sigmoidf(zf) * Cst[hidx] + sigmoidf(zi) * tanh_fast(zg_);
        const float h = sigmoidf(zo) * tanh_fast(cnew);
        Cst[hidx] = cnew;
        Hout[hidx] = f2b(h);
      }
    }
  }
}

// ---------- t=0 LSTM gate: z = P1[0] (permuted layout), c0 = 0 ----------
__global__ void lstm_gate0(const unsigned short* __restrict__ P1_,
                           const float* __restrict__ bias,
                           float* __restrict__ C, unsigned short* __restrict__ H) {
  const int idx = blockIdx.x * 256 + threadIdx.x;   // 512*1024
  const int b = idx >> 10, u = idx & 1023;
  u16x4 z4 = *(const u16x4*)(P1_ + (size_t)b * 4096 + 4 * u);
  const float i_ = b2f(z4[0]) + bias[u];
  const float g_ = b2f(z4[2]) + bias[2048 + u];
  const float o_ = b2f(z4[3]) + bias[3072 + u];
  const float c = sigmoidf(i_) * tanh_fast(g_);     // f-gate * 0 drops out
  const float h = sigmoidf(o_) * tanh_fast(c);
  C[idx] = c;
  H[idx] = f2b(h);
}

// ---------- candidate scoring + softmax: one block per (t,b) row (bf16 tables) ----------
__global__ __launch_bounds__(256) void score_softmax(
    const unsigned short* __restrict__ F2,    // [4096][1024] bf16
    const unsigned short* __restrict__ relB,  // [5000][512] bf16
    const unsigned short* __restrict__ entB,  // [50000][512] bf16
    const int* __restrict__ crel, const int* __restrict__ cent, // [4096][32]
    float* __restrict__ outp) {               // [4096][32] f32
  const int b = blockIdx.x;                   // 0..4095
  const int tid = threadIdx.x;
  const int lane = tid & 63, w = tid >> 6;
  __shared__ float feat[1024];
  __shared__ float logits[32];
  {
    u16x4 fv = ((const u16x4*)(F2 + (size_t)b * 1024))[tid];
#pragma unroll
    for (int j = 0; j < 4; j++) feat[tid * 4 + j] = b2f(fv[j]);
  }
  __syncthreads();
  for (int k = w; k < 32; k += 4) {
    const int ri = crel[b * 32 + k], ei = cent[b * 32 + k];
    u16x8 rv = *(const u16x8*)(relB + (size_t)ri * 512 + lane * 8);
    u16x8 ev = *(const u16x8*)(entB + (size_t)ei * 512 + lane * 8);
    float sum = 0.f;
#pragma unroll
    for (int j = 0; j < 8; j++) {
      sum += b2f(rv[j]) * feat[lane * 8 + j];
      sum += b2f(ev[j]) * feat[512 + lane * 8 + j];
    }
#pragma unroll
    for (int off = 32; off; off >>= 1) sum += __shfl_down(sum, off, 64);
    if (lane == 0) logits[k] = sum;
  }
  __syncthreads();
  if (tid < 32) {
    const float l = logits[tid];
    float mx = l;
#pragma unroll
    for (int off = 16; off; off >>= 1) mx = fmaxf(mx, __shfl_xor(mx, off, 32));
    const float p = __expf(l - mx);
    float s = p;
#pragma unroll
    for (int off = 16; off; off >>= 1) s += __shfl_xor(s, off, 32);
    outp[(size_t)b * 32 + tid] = p / s;
  }
}

// ---------- host launch ----------
extern "C" void kernel_launch(void* const* d_in, const int* in_sizes, int n_in,
                              void* d_out, int out_size, void* d_ws, size_t ws_size,
                              hipStream_t stream) {
  const float* ent      = (const float*)d_in[0];  // [50000][512]
  const float* rel      = (const float*)d_in[1];  // [5000][512]
  const float* relation = (const float*)d_in[2];  // [512][512]
  const float* Wx       = (const float*)d_in[3];  // [1024][4096]
  const float* Wh       = (const float*)d_in[4];  // [1024][4096]
  const float* bvec     = (const float*)d_in[5];  // [4096]
  const float* W1       = (const float*)d_in[6];  // [2048][1536]
  const float* b1       = (const float*)d_in[7];  // [1536]
  const float* W2       = (const float*)d_in[8];  // [1536][1024]
  const float* b2       = (const float*)d_in[9];  // [1024]
  const int* cur  = (const int*)d_in[10];  // [8][512]
  const int* prl  = (const int*)d_in[11];  // [8][512]
  const int* crel = (const int*)d_in[12];  // [8][512][32]
  const int* cent = (const int*)d_in[13];  // [8][512][32]
  float* out = (float*)d_out;              // [8][512][32] f32
  (void)in_sizes; (void)n_in; (void)out_size; (void)ws_size;

  char* wsp = (char*)d_ws;
  auto alloc = [&](size_t bytes) { char* p = wsp; wsp += (bytes + 255) & ~(size_t)255; return p; };
  unsigned short* entB = (unsigned short*)alloc((size_t)50000 * 512 * 2); // [50000][512]
  unsigned short* relB = (unsigned short*)alloc((size_t)5000 * 512 * 2);  // [5000][512]
  unsigned short* rlnB = (unsigned short*)alloc((size_t)512 * 512 * 2);   // [512][512]
  unsigned short* WxT  = (unsigned short*)alloc((size_t)4096 * 1024 * 2); // [4096][1024]
  unsigned short* WhT  = (unsigned short*)alloc((size_t)4096 * 1024 * 2); // [4096][1024]
  unsigned short* W1T  = (unsigned short*)alloc((size_t)1536 * 2048 * 2); // [1536][2048]
  unsigned short* W2T  = (unsigned short*)alloc((size_t)1024 * 1536 * 2); // [1024][1536]
  unsigned short* Xall = (unsigned short*)alloc((size_t)4096 * 1024 * 2); // [8*512][1024]
  unsigned short* ERall= (unsigned short*)alloc((size_t)4096 * 1024 * 2); // [8*512][1024]
  unsigned short* P1   = (unsigned short*)alloc((size_t)4096 * 4096 * 2); // [8*512][4096] perm cols
  unsigned short* Hall = (unsigned short*)alloc((size_t)4096 * 1024 * 2); // [8*512][1024]
  unsigned short* F1   = (unsigned short*)alloc((size_t)4096 * 1536 * 2); // [8*512][1536]
  unsigned short* F2   = (unsigned short*)alloc((size_t)4096 * 1024 * 2); // [8*512][1024]
  float*          C    = (float*)         alloc((size_t)512 * 1024 * 4);  // [512][1024]

  const dim3 blk(256);
  const size_t HS = (size_t)512 * 1024;    // per-step H elements

  // one-time (per launch) prep: bf16 tables + transposed weights
  conv_f2b<<<50000 * 512 / 8 / 256, blk, 0, stream>>>(ent, entB);
  conv_f2b<<<5000 * 512 / 8 / 256, blk, 0, stream>>>(rel, relB);
  conv_f2b<<<512 * 512 / 8 / 256, blk, 0, stream>>>(relation, rlnB);
  transpose_f2b<<<dim3(4096/64, 1024/64), blk, 0, stream>>>(Wx, WxT, 1024, 4096);
  transpose_f2b<<<dim3(4096/64, 1024/64), blk, 0, stream>>>(Wh, WhT, 1024, 4096);
  transpose_f2b<<<dim3(1536/64, 2048/64), blk, 0, stream>>>(W1, W1T, 2048, 1536);
  transpose_f2b<<<dim3(1024/64, 1536/64), blk, 0, stream>>>(W2, W2T, 1536, 1024);
  gather_all<<<4096, 128, 0, stream>>>(entB, relB, rlnB, cur, prl, Xall, ERall);

  // P1 = Xall @ Wx (gate-interleaved cols)   [4096,4096] k=1024
  gemm_bf16<false,false,true,false><<<dim3(32, 32), blk, 0, stream>>>(
      Xall, nullptr, 1024, WxT, 1024, 1024, nullptr, P1, 4096);

  // sequential LSTM chain: t=0 gate-only (h0=0), then fused Z-GEMM+gate per step
  lstm_gate0<<<2048, 256, 0, stream>>>(P1, bvec, C, Hall);
  for (int t = 1; t < 8; t++) {
    zgemm_lstm<<<dim3(32, 8), dim3(512), 0, stream>>>(
        Hall + (size_t)(t - 1) * HS, WhT,
        P1 + (size_t)t * 512 * 4096, bvec,
        Hall + (size_t)t * HS, C);
  }

  // batched posterior MLP over all 8 steps
  // F1 = relu([ent|h|relation] @ W1 + b1)   [4096,1536] k=2048 (A 3-way split)
  gemm_bf16<true,true,false,true><<<dim3(12, 32), blk, 0, stream>>>(
      ERall, Hall, 1024, W1T, 2048, 2048, b1, F1, 1536);
  // F2 = relu(F1 @ W2 + b2)                 [4096,1024] k=1536
  gemm_bf16<true,true,false,false><<<dim3(8, 32), blk, 0, stream>>>(
      F1, nullptr, 1536, W2T, 1536, 1536, b2, F2, 1024);
  // candidate scoring + softmax for all steps
  score_softmax<<<4096, 256, 0, stream>>>(F2, relB, entB, crel, cent, out);
}